// Round 2
// baseline (1185.553 us; speedup 1.0000x reference)
//
#include <hip/hip_runtime.h>
#include <math.h>

#define B_ 16
#define T_ 4096
#define D_ 1024
#define HID_ 1365
#define NPAD 1408            // 88*16
#define NGRP 88              // NPAD/16
#define N_TOK (B_*T_)
#define RHO_ 0.2f
#define LN_EPS_ 1e-5f
#define SC 1024.0f
#define INV_SC2 (1.0f/(1024.0f*1024.0f))

#define NHT 11               // h-tiles of 128
#define WCHUNKS (NGRP*32*4*16)       // 180224 f16x8 chunks
#define NG16 4096            // 16-token groups
#define ACHUNKS ((size_t)NG16*32*64) // 8388608 f16x8 chunks per buffer

typedef _Float16 f16x8 __attribute__((ext_vector_type(8)));
typedef float f32x4 __attribute__((ext_vector_type(4)));

// async global->LDS, 16B per lane; LDS dest = wave-uniform base + lane*16
__device__ __forceinline__ void gl16(const void* g, void* l) {
  __builtin_amdgcn_global_load_lds(
      (const __attribute__((address_space(1))) unsigned int*)g,
      (__attribute__((address_space(3))) unsigned int*)l, 16, 0, 0);
}

// ---------------- Kernel 1b: split fc1_w (x1024) into hi/lo f16 in MFMA-frag order ---
__global__ __launch_bounds__(256) void wsplit_kernel(
    const float* __restrict__ fc1w, f16x8* __restrict__ whi, f16x8* __restrict__ wlo)
{
  int c = blockIdx.x * 256 + threadIdx.x;
  if (c >= WCHUNKS) return;
  int ln = c & 15, q = (c >> 4) & 3, ks = (c >> 6) & 31, g = c >> 11;
  int n = g * 16 + ln;
  int k = ks * 32 + q * 8;
  f16x8 hi, lo;
#pragma unroll
  for (int j = 0; j < 8; ++j) {
    float v = (n < HID_) ? fc1w[(size_t)n * D_ + k + j] * SC : 0.f;
    _Float16 h = (_Float16)v;
    hi[j] = h;
    lo[j] = (_Float16)(v - (float)h);
  }
  whi[c] = hi;
  wlo[c] = lo;
}

// ---------------- Kernel 1c (fused): LN stats + LN-apply + hi/lo split, frag order ---
#define FSTR 1028
__global__ __launch_bounds__(256, 2) void lnasplit_kernel(
    const float* __restrict__ emb, const float* __restrict__ attn,
    const float* __restrict__ lnw, const float* __restrict__ lnb,
    f16x8* __restrict__ ahi, f16x8* __restrict__ alo)
{
  __shared__ float tile[16 * FSTR];
  __shared__ float smu[16], srs[16];
  int tid = threadIdx.x;
  int g = blockIdx.x;
  int wave = tid >> 6, lane = tid & 63;
#pragma unroll
  for (int it = 0; it < 16; ++it) {
    int idx = tid + it * 256;
    int row = idx >> 8, c4 = idx & 255;
    float a = attn[g * 16 + row];
    float4 v = *reinterpret_cast<const float4*>(
        emb + (size_t)(g * 16 + row) * D_ + c4 * 4);
    v.x *= a; v.y *= a; v.z *= a; v.w *= a;
    *reinterpret_cast<float4*>(&tile[row * FSTR + c4 * 4]) = v;
  }
  __syncthreads();
#pragma unroll
  for (int r4 = 0; r4 < 4; ++r4) {
    int row = wave * 4 + r4;
    float s = 0.f, sq = 0.f;
#pragma unroll
    for (int q = 0; q < 4; ++q) {
      float4 v = *reinterpret_cast<const float4*>(&tile[row * FSTR + lane * 4 + q * 256]);
      s  += v.x + v.y + v.z + v.w;
      sq += v.x * v.x + v.y * v.y + v.z * v.z + v.w * v.w;
    }
#pragma unroll
    for (int off = 32; off > 0; off >>= 1) {
      s  += __shfl_down(s, off, 64);
      sq += __shfl_down(sq, off, 64);
    }
    if (lane == 0) {
      float m = s * (1.f / D_);
      float var = sq * (1.f / D_) - m * m;
      if (var < 0.f) var = 0.f;
      smu[row] = m;
      srs[row] = 1.f / sqrtf(var + LN_EPS_);
    }
  }
  __syncthreads();
#pragma unroll
  for (int it = 0; it < 8; ++it) {
    int idx = tid + it * 256;
    int ksl = idx >> 6, l = idx & 63;
    int ln = l & 15, q = l >> 4;
    float rs = srs[ln];
    float nmr = -smu[ln] * rs;
    int colbase = ksl * 32 + q * 8;
    float4 e0 = *reinterpret_cast<const float4*>(&tile[ln * FSTR + colbase]);
    float4 e1 = *reinterpret_cast<const float4*>(&tile[ln * FSTR + colbase + 4]);
    float ev[8] = {e0.x, e0.y, e0.z, e0.w, e1.x, e1.y, e1.z, e1.w};
    f16x8 hi, lo;
#pragma unroll
    for (int j = 0; j < 8; ++j) {
      int kg = colbase + j;
      float wv = lnw[kg], bv = lnb[kg];
      float y = fmaf(ev[j] * rs, wv, fmaf(nmr, wv, bv)) * SC;
      _Float16 h = (_Float16)y;
      hi[j] = h;
      lo[j] = (_Float16)(y - (float)h);
    }
    size_t c = (size_t)(g * 32 + ksl) * 64 + l;
    ahi[c] = hi;
    alo[c] = lo;
  }
}

// ---------------- Kernel 2 (v6): triple-buffered counted-vmcnt MFMA GEMM ------------
// 512 thr = 8 waves (4 wrow x 2 wcol); block tile 256 tok x 128 h; wave tile 64x64.
// LDS: 3 slice-buffers of 48KB [Ahi 16K | Alo 16K | Bhi 8K | Blo 8K], staged 2 slices
// ahead via global_load_lds (6 x 1KB per wave per step). Step end waits vmcnt(6) —
// the just-issued 6 loads stay in flight across the barrier (T3+T4); setprio around
// the MFMA cluster (T5). Accumulation order identical to v4/v5 (bit-exact output).
__global__ __launch_bounds__(512, 2) void mfma_score_v6(
    const f16x8* __restrict__ ahi, const f16x8* __restrict__ alo,
    const f16x8* __restrict__ whi, const f16x8* __restrict__ wlo,
    const float* __restrict__ fc1b, const float* __restrict__ fc2w,
    float* __restrict__ partial)
{
  __shared__ f16x8 sbuf[3][3072];   // 3 x 48KB
  __shared__ float red[2][256];
  int tid = threadIdx.x, lane = tid & 63;
  int w = tid >> 6, wrow = w & 3, wcol = w >> 2;
  // XCD-aware swizzle: the 11 ht-blocks of one 256-token tile stay on one XCD
  int flat = blockIdx.x;            // 0..2815 = 8 XCDs * (32 tb * 11 ht)
  int xcd = flat & 7, j = flat >> 3;
  int tb = xcd * 32 + j / NHT;      // 0..255 token-tiles of 256
  int ht = j % NHT;                 // 0..10
  int g0 = tb * 16;                 // 16 token-groups of 16 per block
  int hb0 = ht * 8;                 // 8 h-groups of 16 per block
  int ln16 = lane & 15, quad = lane >> 4;

  // per-wave staging sources: 48 1KB-units per slice; wave w owns units w*6..w*6+5
  int u0 = w * 6;
  const f16x8* sp[6];
#pragma unroll
  for (int i = 0; i < 6; ++i) {
    int u = u0 + i;
    const f16x8* base;
    int grp;
    if (u < 16)      { base = ahi; grp = g0 + u; }
    else if (u < 32) { base = alo; grp = g0 + (u - 16); }
    else if (u < 40) { base = whi; grp = hb0 + (u - 32); }
    else             { base = wlo; grp = hb0 + (u - 40); }
    sp[i] = base + (size_t)grp * 2048 + lane;   // 32 slices * 64 chunks per group
  }

#define STAGE6(BUF, KS)                                                \
  _Pragma("unroll")                                                    \
  for (int i = 0; i < 6; ++i)                                          \
    gl16(sp[i] + (size_t)(KS) * 64, &sbuf[BUF][(u0 + i) * 64]);

#define DOSTEP(KS, CUR, STG, VMSTR)                                    \
  {                                                                    \
    if (STG) { STAGE6(((CUR) + 2) % 3, (KS) + 2); }                    \
    f16x8 ah[4], al[4], bh[4], bl[4];                                  \
    _Pragma("unroll")                                                  \
    for (int mi = 0; mi < 4; ++mi) {                                   \
      ah[mi] = sbuf[CUR][(wrow * 4 + mi) * 64 + lane];                 \
      al[mi] = sbuf[CUR][1024 + (wrow * 4 + mi) * 64 + lane];          \
    }                                                                  \
    _Pragma("unroll")                                                  \
    for (int nj = 0; nj < 4; ++nj) {                                   \
      bh[nj] = sbuf[CUR][2048 + (wcol * 4 + nj) * 64 + lane];          \
      bl[nj] = sbuf[CUR][2560 + (wcol * 4 + nj) * 64 + lane];          \
    }                                                                  \
    __builtin_amdgcn_s_setprio(1);                                     \
    _Pragma("unroll")                                                  \
    for (int mi = 0; mi < 4; ++mi)                                     \
      _Pragma("unroll")                                                \
      for (int nj = 0; nj < 4; ++nj) {                                 \
        acc[mi][nj] = __builtin_amdgcn_mfma_f32_16x16x32_f16(ah[mi], bh[nj], acc[mi][nj], 0, 0, 0); \
        acc[mi][nj] = __builtin_amdgcn_mfma_f32_16x16x32_f16(al[mi], bh[nj], acc[mi][nj], 0, 0, 0); \
        acc[mi][nj] = __builtin_amdgcn_mfma_f32_16x16x32_f16(ah[mi], bl[nj], acc[mi][nj], 0, 0, 0); \
      }                                                                \
    __builtin_amdgcn_s_setprio(0);                                     \
    __builtin_amdgcn_sched_barrier(0);                                 \
    asm volatile("s_waitcnt " VMSTR ::: "memory");                     \
    __builtin_amdgcn_s_barrier();                                      \
  }

  f32x4 acc[4][4];
#pragma unroll
  for (int i = 0; i < 4; ++i)
#pragma unroll
    for (int j2 = 0; j2 < 4; ++j2) acc[i][j2] = (f32x4)0.f;

  // prologue: stage slices 0 and 1; wait for slice 0 only (6 of slice 1 stay in flight)
  STAGE6(0, 0);
  STAGE6(1, 1);
  __builtin_amdgcn_sched_barrier(0);
  asm volatile("s_waitcnt vmcnt(6)" ::: "memory");
  __builtin_amdgcn_s_barrier();

#pragma unroll 1
  for (int kt = 0; kt < 30; kt += 3) {
    DOSTEP(kt,     0, 1, "vmcnt(6)");
    DOSTEP(kt + 1, 1, 1, "vmcnt(6)");
    DOSTEP(kt + 2, 2, 1, "vmcnt(6)");
  }
  DOSTEP(30, 0, 0, "vmcnt(0)");
  DOSTEP(31, 1, 0, "vmcnt(0)");

#undef DOSTEP
#undef STAGE6

  // ---- epilogue: bias + exact GELU + fc2 weight, reduce over hidden ----
  int gb0 = hb0 + wcol * 4;
  float s[4][4];
#pragma unroll
  for (int mi = 0; mi < 4; ++mi)
#pragma unroll
    for (int r = 0; r < 4; ++r) s[mi][r] = 0.f;
#pragma unroll
  for (int nj = 0; nj < 4; ++nj) {
    int h = (gb0 + nj) * 16 + ln16;
    float b1 = 0.f, w2 = 0.f;
    if (h < HID_) { b1 = fc1b[h]; w2 = fc2w[h]; }
#pragma unroll
    for (int mi = 0; mi < 4; ++mi)
#pragma unroll
      for (int r = 0; r < 4; ++r) {
        float v = acc[mi][nj][r] * INV_SC2 + b1;
        float gel = 0.5f * v * (1.f + erff(v * 0.70710678118654752440f));
        s[mi][r] = fmaf(gel, w2, s[mi][r]);
      }
  }
#pragma unroll
  for (int mi = 0; mi < 4; ++mi)
#pragma unroll
    for (int r = 0; r < 4; ++r) {
      float v = s[mi][r];
      v += __shfl_xor(v, 1, 64);
      v += __shfl_xor(v, 2, 64);
      v += __shfl_xor(v, 4, 64);
      v += __shfl_xor(v, 8, 64);
      s[mi][r] = v;
    }
  if (ln16 == 0) {
#pragma unroll
    for (int mi = 0; mi < 4; ++mi)
#pragma unroll
      for (int r = 0; r < 4; ++r)
        red[wcol][wrow * 64 + mi * 16 + quad * 4 + r] = s[mi][r];
  }
  __syncthreads();
  if (tid < 256)
    partial[(size_t)ht * N_TOK + tb * 256 + tid] = red[0][tid] + red[1][tid];
}

// ---------------- Kernel 3: slab-reduce + masked softmax + entropy + K + z ----------
__global__ __launch_bounds__(1024) void softmax_kernel(
    const float* __restrict__ partial, const float* __restrict__ fc2b,
    const float* __restrict__ attn,
    float* __restrict__ out_z, float* __restrict__ rowent, float* __restrict__ rowK)
{
  __shared__ float buf[1024];
  int b = blockIdx.x, tid = threadIdx.x;
  const float* arow = attn + b * T_;
  float sv[4], av[4];
  float f2b = fc2b[0];
#pragma unroll
  for (int q = 0; q < 4; ++q) {
    int t = tid + q * 1024;
    av[q] = arow[t];
    float sc = f2b;
#pragma unroll
    for (int p = 0; p < NHT; ++p) sc += partial[(size_t)p * N_TOK + b * T_ + t];
    sv[q] = (av[q] == 0.f) ? -1e9f : sc;
  }
  float m = fmaxf(fmaxf(sv[0], sv[1]), fmaxf(sv[2], sv[3]));
  buf[tid] = m; __syncthreads();
  for (int s = 512; s > 0; s >>= 1) { if (tid < s) buf[tid] = fmaxf(buf[tid], buf[tid + s]); __syncthreads(); }
  m = buf[0]; __syncthreads();
  float e[4]; float es = 0.f, as = 0.f;
#pragma unroll
  for (int q = 0; q < 4; ++q) { e[q] = expf(sv[q] - m); es += e[q]; as += av[q]; }
  buf[tid] = es; __syncthreads();
  for (int s = 512; s > 0; s >>= 1) { if (tid < s) buf[tid] += buf[tid + s]; __syncthreads(); }
  es = buf[0]; __syncthreads();
  buf[tid] = as; __syncthreads();
  for (int s = 512; s > 0; s >>= 1) { if (tid < s) buf[tid] += buf[tid + s]; __syncthreads(); }
  as = buf[0]; __syncthreads();
  float K = fmaxf(1.f, rintf(RHO_ * as));
  float inv = 1.f / es;
  float ent = 0.f;
#pragma unroll
  for (int q = 0; q < 4; ++q) {
    float p = e[q] * inv;
    out_z[b * T_ + tid + q * 1024] = K * p;
    ent -= p * logf(p + 1e-12f);
  }
  buf[tid] = ent; __syncthreads();
  for (int s = 512; s > 0; s >>= 1) { if (tid < s) buf[tid] += buf[tid + s]; __syncthreads(); }
  if (tid == 0) {
    rowent[b] = buf[0] / logf(fmaxf(as, 1.f));
    rowK[b] = K;
  }
}

// ---------------- Kernel 4: per-row exact top-K mask (stable ties) + scalar out ----
__global__ __launch_bounds__(1024) void topk_kernel(
    const float* __restrict__ zall, float* __restrict__ g,
    const float* __restrict__ rowent, const float* __restrict__ rowK,
    float* __restrict__ out_scalar)
{
  __shared__ float sm[T_];
  __shared__ int s_first, s_last;
  int b = blockIdx.x, tid = threadIdx.x;
  const float* zrow = zall + b * T_;
  for (int t = tid; t < T_; t += 1024) sm[t] = zrow[t];
  __syncthreads();
  for (int k = 2; k <= T_; k <<= 1) {
    for (int j = k >> 1; j > 0; j >>= 1) {
      for (int t = tid; t < T_; t += 1024) {
        int ixj = t ^ j;
        if (ixj > t) {
          float a = sm[t], c = sm[ixj];
          bool desc = ((t & k) == 0);
          if (desc ? (a < c) : (a > c)) { sm[t] = c; sm[ixj] = a; }
        }
      }
      __syncthreads();
    }
  }
  int K = (int)rowK[b];
  float thr = sm[K - 1];
  if (tid == 0) { s_first = T_; s_last = -1; }
  __syncthreads();
  for (int t = tid; t < T_; t += 1024) {
    if (sm[t] == thr) { atomicMin(&s_first, t); atomicMax(&s_last, t); }
  }
  __syncthreads();
  int cgt = s_first;
  int eqTotal = s_last - s_first + 1;
  int need = K - cgt;
  float* grow = g + b * T_;
  bool allEq = (eqTotal == need);
  for (int t = tid; t < T_; t += 1024) {
    float zv = zrow[t];
    if (zv > thr) grow[t] = 1.f;
    else if (zv < thr) grow[t] = 0.f;
    else if (allEq) grow[t] = 1.f;
  }
  __syncthreads();
  if (!allEq && tid == 0) {
    int cnt = 0;
    for (int t = 0; t < T_; ++t) {
      float zv = zrow[t];
      if (zv == thr) { grow[t] = (cnt < need) ? 1.f : 0.f; ++cnt; }
    }
  }
  if (b == 0 && tid == 0) {
    float s = 0.f;
    for (int i = 0; i < B_; ++i) s += rowent[i];
    out_scalar[0] = s * (1.f / B_);
  }
}

extern "C" void kernel_launch(void* const* d_in, const int* in_sizes, int n_in,
                              void* d_out, int out_size, void* d_ws, size_t ws_size,
                              hipStream_t stream)
{
  const float* emb  = (const float*)d_in[0];
  const float* attn = (const float*)d_in[1];
  const float* lnw  = (const float*)d_in[2];
  const float* lnb  = (const float*)d_in[3];
  const float* fc1w = (const float*)d_in[4];
  const float* fc1b = (const float*)d_in[5];
  const float* fc2w = (const float*)d_in[6];
  const float* fc2b = (const float*)d_in[7];

  float* out = (float*)d_out;
  float* g  = out;
  float* z  = out + N_TOK;
  float* ns = out + 2 * N_TOK;

  float* mu      = (float*)d_ws;                    // (unused slot, layout kept)
  float* rstd    = mu + N_TOK;                      // (unused slot, layout kept)
  float* partial = rstd + N_TOK;                    // NHT*N_TOK
  float* rowent  = partial + (size_t)NHT * N_TOK;   // 16
  float* rowK    = rowent + 16;                     // 16
  f16x8* whi     = (f16x8*)(rowK + 16);             // WCHUNKS
  f16x8* wlo     = whi + WCHUNKS;
  f16x8* ahi     = wlo + WCHUNKS;                   // ACHUNKS
  f16x8* alo     = ahi + ACHUNKS;

  wsplit_kernel<<<(WCHUNKS + 255) / 256, 256, 0, stream>>>(fc1w, whi, wlo);
  lnasplit_kernel<<<NG16, 256, 0, stream>>>(emb, attn, lnw, lnb, ahi, alo);
  mfma_score_v6<<<8 * 32 * NHT, 512, 0, stream>>>(ahi, alo, whi, wlo, fc1b, fc2w, partial);
  softmax_kernel<<<B_, 1024, 0, stream>>>(partial, fc2b, attn, z, rowent, rowK);
  topk_kernel<<<B_, 1024, 0, stream>>>(z, g, rowent, rowK, ns);
}

// Round 3
// 1150.309 us; speedup vs baseline: 1.0306x; 1.0306x over previous
//
#include <hip/hip_runtime.h>
#include <math.h>

#define B_ 16
#define T_ 4096
#define D_ 1024
#define HID_ 1365
#define NPAD 1408            // 88*16
#define NGRP 88              // NPAD/16
#define N_TOK (B_*T_)
#define RHO_ 0.2f
#define LN_EPS_ 1e-5f
#define SC 1024.0f
#define INV_SC2 (1.0f/(1024.0f*1024.0f))

#define NHT 11               // h-tiles of 128
#define WCHUNKS (NGRP*32*4*16)       // 180224 f16x8 chunks
#define NG16 4096            // 16-token groups
#define ACHUNKS ((size_t)NG16*32*64) // 8388608 f16x8 chunks per buffer

typedef _Float16 f16x8 __attribute__((ext_vector_type(8)));
typedef float f32x4 __attribute__((ext_vector_type(4)));

// async global->LDS, 16B per lane; LDS dest = wave-uniform base + lane*16
__device__ __forceinline__ void gl16(const void* g, void* l) {
  __builtin_amdgcn_global_load_lds(
      (const __attribute__((address_space(1))) unsigned int*)g,
      (__attribute__((address_space(3))) unsigned int*)l, 16, 0, 0);
}

// ---------------- Kernel 1b: split fc1_w (x1024) into hi/lo f16 in MFMA-frag order ---
__global__ __launch_bounds__(256) void wsplit_kernel(
    const float* __restrict__ fc1w, f16x8* __restrict__ whi, f16x8* __restrict__ wlo)
{
  int c = blockIdx.x * 256 + threadIdx.x;
  if (c >= WCHUNKS) return;
  int ln = c & 15, q = (c >> 4) & 3, ks = (c >> 6) & 31, g = c >> 11;
  int n = g * 16 + ln;
  int k = ks * 32 + q * 8;
  f16x8 hi, lo;
#pragma unroll
  for (int j = 0; j < 8; ++j) {
    float v = (n < HID_) ? fc1w[(size_t)n * D_ + k + j] * SC : 0.f;
    _Float16 h = (_Float16)v;
    hi[j] = h;
    lo[j] = (_Float16)(v - (float)h);
  }
  whi[c] = hi;
  wlo[c] = lo;
}

// ---------------- Kernel 1c (fused): LN stats + LN-apply + hi/lo split, frag order ---
#define FSTR 1028
__global__ __launch_bounds__(256, 2) void lnasplit_kernel(
    const float* __restrict__ emb, const float* __restrict__ attn,
    const float* __restrict__ lnw, const float* __restrict__ lnb,
    f16x8* __restrict__ ahi, f16x8* __restrict__ alo)
{
  __shared__ float tile[16 * FSTR];
  __shared__ float smu[16], srs[16];
  int tid = threadIdx.x;
  int g = blockIdx.x;
  int wave = tid >> 6, lane = tid & 63;
#pragma unroll
  for (int it = 0; it < 16; ++it) {
    int idx = tid + it * 256;
    int row = idx >> 8, c4 = idx & 255;
    float a = attn[g * 16 + row];
    float4 v = *reinterpret_cast<const float4*>(
        emb + (size_t)(g * 16 + row) * D_ + c4 * 4);
    v.x *= a; v.y *= a; v.z *= a; v.w *= a;
    *reinterpret_cast<float4*>(&tile[row * FSTR + c4 * 4]) = v;
  }
  __syncthreads();
#pragma unroll
  for (int r4 = 0; r4 < 4; ++r4) {
    int row = wave * 4 + r4;
    float s = 0.f, sq = 0.f;
#pragma unroll
    for (int q = 0; q < 4; ++q) {
      float4 v = *reinterpret_cast<const float4*>(&tile[row * FSTR + lane * 4 + q * 256]);
      s  += v.x + v.y + v.z + v.w;
      sq += v.x * v.x + v.y * v.y + v.z * v.z + v.w * v.w;
    }
#pragma unroll
    for (int off = 32; off > 0; off >>= 1) {
      s  += __shfl_down(s, off, 64);
      sq += __shfl_down(sq, off, 64);
    }
    if (lane == 0) {
      float m = s * (1.f / D_);
      float var = sq * (1.f / D_) - m * m;
      if (var < 0.f) var = 0.f;
      smu[row] = m;
      srs[row] = 1.f / sqrtf(var + LN_EPS_);
    }
  }
  __syncthreads();
#pragma unroll
  for (int it = 0; it < 8; ++it) {
    int idx = tid + it * 256;
    int ksl = idx >> 6, l = idx & 63;
    int ln = l & 15, q = l >> 4;
    float rs = srs[ln];
    float nmr = -smu[ln] * rs;
    int colbase = ksl * 32 + q * 8;
    float4 e0 = *reinterpret_cast<const float4*>(&tile[ln * FSTR + colbase]);
    float4 e1 = *reinterpret_cast<const float4*>(&tile[ln * FSTR + colbase + 4]);
    float ev[8] = {e0.x, e0.y, e0.z, e0.w, e1.x, e1.y, e1.z, e1.w};
    f16x8 hi, lo;
#pragma unroll
    for (int j = 0; j < 8; ++j) {
      int kg = colbase + j;
      float wv = lnw[kg], bv = lnb[kg];
      float y = fmaf(ev[j] * rs, wv, fmaf(nmr, wv, bv)) * SC;
      _Float16 h = (_Float16)y;
      hi[j] = h;
      lo[j] = (_Float16)(y - (float)h);
    }
    size_t c = (size_t)(g * 32 + ksl) * 64 + l;
    ahi[c] = hi;
    alo[c] = lo;
  }
}

// ---------------- Kernel 2 (v7): 3-phase m201-style double-buffered MFMA GEMM -------
// 512 thr = 8 waves (4 wrow x 2 wcol); block tile 256 tok x 128 h; wave tile 64x64.
// LDS: 2 slice-buffers of 48KB. Per K-step, 3 phases split by product:
//   P0: read ah+bh (8 ds_read) + issue STAGE6(next slice) -> bar -> lgkm0 -> 16 hh MFMA -> bar
//   P1: read al (4)                                       -> bar -> lgkm0 -> 16 lh MFMA -> bar
//   P2: read bl (4)                                       -> bar -> lgkm0 -> 16 hl MFMA
//   step end: vmcnt(0) (stage issued ~2.5 phases earlier -> nearly free) -> bar
// Per-acc order hh,lh,hl preserved => bit-exact vs v4/v5/v6.
__global__ __launch_bounds__(512, 2) void mfma_score_v7(
    const f16x8* __restrict__ ahi, const f16x8* __restrict__ alo,
    const f16x8* __restrict__ whi, const f16x8* __restrict__ wlo,
    const float* __restrict__ fc1b, const float* __restrict__ fc2w,
    float* __restrict__ partial)
{
  __shared__ f16x8 sbuf[2][3072];   // 2 x 48KB
  __shared__ float red[2][256];
  int tid = threadIdx.x, lane = tid & 63;
  int w = tid >> 6, wrow = w & 3, wcol = w >> 2;
  // XCD-aware swizzle: the 11 ht-blocks of one 256-token tile stay on one XCD
  int flat = blockIdx.x;            // 0..2815 = 8 XCDs * (32 tb * 11 ht)
  int xcd = flat & 7, j = flat >> 3;
  int tb = xcd * 32 + j / NHT;      // 0..255 token-tiles of 256
  int ht = j % NHT;                 // 0..10
  int g0 = tb * 16;                 // 16 token-groups of 16 per block
  int hb0 = ht * 8;                 // 8 h-groups of 16 per block
  int ln16 = lane & 15, quad = lane >> 4;

  // per-wave staging sources: 48 1KB-units per slice; wave w owns units w*6..w*6+5
  int u0 = w * 6;
  const f16x8* sp[6];
#pragma unroll
  for (int i = 0; i < 6; ++i) {
    int u = u0 + i;
    const f16x8* base;
    int grp;
    if (u < 16)      { base = ahi; grp = g0 + u; }
    else if (u < 32) { base = alo; grp = g0 + (u - 16); }
    else if (u < 40) { base = whi; grp = hb0 + (u - 32); }
    else             { base = wlo; grp = hb0 + (u - 40); }
    sp[i] = base + (size_t)grp * 2048 + lane;   // 32 slices * 64 chunks per group
  }

#define PBAR() do { __builtin_amdgcn_sched_barrier(0); \
                    __builtin_amdgcn_s_barrier();      \
                    __builtin_amdgcn_sched_barrier(0); } while (0)
#define LG0()  do { asm volatile("s_waitcnt lgkmcnt(0)" ::: "memory"); \
                    __builtin_amdgcn_sched_barrier(0); } while (0)

  f32x4 acc[4][4];
#pragma unroll
  for (int i = 0; i < 4; ++i)
#pragma unroll
    for (int j2 = 0; j2 < 4; ++j2) acc[i][j2] = (f32x4)0.f;

  // prologue: stage slice 0 into buffer 0, wait, barrier
#pragma unroll
  for (int i = 0; i < 6; ++i)
    gl16(sp[i], &sbuf[0][(u0 + i) * 64]);
  __builtin_amdgcn_sched_barrier(0);
  asm volatile("s_waitcnt vmcnt(0)" ::: "memory");
  __builtin_amdgcn_s_barrier();
  __builtin_amdgcn_sched_barrier(0);

#pragma unroll 1
  for (int ks = 0; ks < 32; ++ks) {
    int cur = ks & 1;
    const f16x8* sb = &sbuf[cur][0];
    f16x8* nb = &sbuf[cur ^ 1][0];

    // ---- P0: ah + bh reads, stage next slice, hh products ----
    f16x8 ah[4], bh[4];
#pragma unroll
    for (int mi = 0; mi < 4; ++mi) ah[mi] = sb[(wrow * 4 + mi) * 64 + lane];
#pragma unroll
    for (int nj = 0; nj < 4; ++nj) bh[nj] = sb[2048 + (wcol * 4 + nj) * 64 + lane];
    if (ks < 31) {
#pragma unroll
      for (int i = 0; i < 6; ++i)
        gl16(sp[i] + (size_t)(ks + 1) * 64, &nb[(u0 + i) * 64]);
    }
    PBAR();
    LG0();
    __builtin_amdgcn_s_setprio(1);
#pragma unroll
    for (int mi = 0; mi < 4; ++mi)
#pragma unroll
      for (int nj = 0; nj < 4; ++nj)
        acc[mi][nj] = __builtin_amdgcn_mfma_f32_16x16x32_f16(ah[mi], bh[nj], acc[mi][nj], 0, 0, 0);
    __builtin_amdgcn_s_setprio(0);
    PBAR();

    // ---- P1: al reads, lh products ----
    f16x8 al[4];
#pragma unroll
    for (int mi = 0; mi < 4; ++mi) al[mi] = sb[1024 + (wrow * 4 + mi) * 64 + lane];
    PBAR();
    LG0();
    __builtin_amdgcn_s_setprio(1);
#pragma unroll
    for (int mi = 0; mi < 4; ++mi)
#pragma unroll
      for (int nj = 0; nj < 4; ++nj)
        acc[mi][nj] = __builtin_amdgcn_mfma_f32_16x16x32_f16(al[mi], bh[nj], acc[mi][nj], 0, 0, 0);
    __builtin_amdgcn_s_setprio(0);
    PBAR();

    // ---- P2: bl reads, hl products ----
    f16x8 bl[4];
#pragma unroll
    for (int nj = 0; nj < 4; ++nj) bl[nj] = sb[2560 + (wcol * 4 + nj) * 64 + lane];
    PBAR();
    LG0();
    __builtin_amdgcn_s_setprio(1);
#pragma unroll
    for (int mi = 0; mi < 4; ++mi)
#pragma unroll
      for (int nj = 0; nj < 4; ++nj)
        acc[mi][nj] = __builtin_amdgcn_mfma_f32_16x16x32_f16(ah[mi], bl[nj], acc[mi][nj], 0, 0, 0);
    __builtin_amdgcn_s_setprio(0);
    // step end: stage loads (issued in P0) must have landed before next step reads nb
    __builtin_amdgcn_sched_barrier(0);
    asm volatile("s_waitcnt vmcnt(0)" ::: "memory");
    __builtin_amdgcn_s_barrier();
    __builtin_amdgcn_sched_barrier(0);
  }

#undef PBAR
#undef LG0

  // ---- epilogue: bias + exact GELU + fc2 weight, reduce over hidden ----
  int gb0 = hb0 + wcol * 4;
  float s[4][4];
#pragma unroll
  for (int mi = 0; mi < 4; ++mi)
#pragma unroll
    for (int r = 0; r < 4; ++r) s[mi][r] = 0.f;
#pragma unroll
  for (int nj = 0; nj < 4; ++nj) {
    int h = (gb0 + nj) * 16 + ln16;
    float b1 = 0.f, w2 = 0.f;
    if (h < HID_) { b1 = fc1b[h]; w2 = fc2w[h]; }
#pragma unroll
    for (int mi = 0; mi < 4; ++mi)
#pragma unroll
      for (int r = 0; r < 4; ++r) {
        float v = acc[mi][nj][r] * INV_SC2 + b1;
        float gel = 0.5f * v * (1.f + erff(v * 0.70710678118654752440f));
        s[mi][r] = fmaf(gel, w2, s[mi][r]);
      }
  }
#pragma unroll
  for (int mi = 0; mi < 4; ++mi)
#pragma unroll
    for (int r = 0; r < 4; ++r) {
      float v = s[mi][r];
      v += __shfl_xor(v, 1, 64);
      v += __shfl_xor(v, 2, 64);
      v += __shfl_xor(v, 4, 64);
      v += __shfl_xor(v, 8, 64);
      s[mi][r] = v;
    }
  if (ln16 == 0) {
#pragma unroll
    for (int mi = 0; mi < 4; ++mi)
#pragma unroll
      for (int r = 0; r < 4; ++r)
        red[wcol][wrow * 64 + mi * 16 + quad * 4 + r] = s[mi][r];
  }
  __syncthreads();
  if (tid < 256)
    partial[(size_t)ht * N_TOK + tb * 256 + tid] = red[0][tid] + red[1][tid];
}

// ---------------- Kernel 3: slab-reduce + masked softmax + entropy + K + z ----------
__global__ __launch_bounds__(1024) void softmax_kernel(
    const float* __restrict__ partial, const float* __restrict__ fc2b,
    const float* __restrict__ attn,
    float* __restrict__ out_z, float* __restrict__ rowent, float* __restrict__ rowK)
{
  __shared__ float buf[1024];
  int b = blockIdx.x, tid = threadIdx.x;
  const float* arow = attn + b * T_;
  float sv[4], av[4];
  float f2b = fc2b[0];
#pragma unroll
  for (int q = 0; q < 4; ++q) {
    int t = tid + q * 1024;
    av[q] = arow[t];
    float sc = f2b;
#pragma unroll
    for (int p = 0; p < NHT; ++p) sc += partial[(size_t)p * N_TOK + b * T_ + t];
    sv[q] = (av[q] == 0.f) ? -1e9f : sc;
  }
  float m = fmaxf(fmaxf(sv[0], sv[1]), fmaxf(sv[2], sv[3]));
  buf[tid] = m; __syncthreads();
  for (int s = 512; s > 0; s >>= 1) { if (tid < s) buf[tid] = fmaxf(buf[tid], buf[tid + s]); __syncthreads(); }
  m = buf[0]; __syncthreads();
  float e[4]; float es = 0.f, as = 0.f;
#pragma unroll
  for (int q = 0; q < 4; ++q) { e[q] = expf(sv[q] - m); es += e[q]; as += av[q]; }
  buf[tid] = es; __syncthreads();
  for (int s = 512; s > 0; s >>= 1) { if (tid < s) buf[tid] += buf[tid + s]; __syncthreads(); }
  es = buf[0]; __syncthreads();
  buf[tid] = as; __syncthreads();
  for (int s = 512; s > 0; s >>= 1) { if (tid < s) buf[tid] += buf[tid + s]; __syncthreads(); }
  as = buf[0]; __syncthreads();
  float K = fmaxf(1.f, rintf(RHO_ * as));
  float inv = 1.f / es;
  float ent = 0.f;
#pragma unroll
  for (int q = 0; q < 4; ++q) {
    float p = e[q] * inv;
    out_z[b * T_ + tid + q * 1024] = K * p;
    ent -= p * logf(p + 1e-12f);
  }
  buf[tid] = ent; __syncthreads();
  for (int s = 512; s > 0; s >>= 1) { if (tid < s) buf[tid] += buf[tid + s]; __syncthreads(); }
  if (tid == 0) {
    rowent[b] = buf[0] / logf(fmaxf(as, 1.f));
    rowK[b] = K;
  }
}

// ---------------- Kernel 4 (v2): radix-256 select top-K (stable ties) + scalar out --
// z >= +0 always (K*p, p>=0), so uint bit pattern is order-isomorphic to float.
__global__ __launch_bounds__(1024) void topk_kernel(
    const float* __restrict__ zall, float* __restrict__ g,
    const float* __restrict__ rowent, const float* __restrict__ rowK,
    float* __restrict__ out_scalar)
{
  __shared__ unsigned hist[256];
  __shared__ unsigned s_prefix, s_kk;
  __shared__ int s_cgt, s_ceq;
  int b = blockIdx.x, tid = threadIdx.x;
  const float* zrow = zall + b * T_;
  unsigned zb[4];
#pragma unroll
  for (int q = 0; q < 4; ++q) zb[q] = __float_as_uint(zrow[tid + q * 1024]);
  int K = (int)rowK[b];

  unsigned prefix = 0;
  unsigned kk = (unsigned)K;          // 1-indexed rank from the top
#pragma unroll
  for (int pass = 0; pass < 4; ++pass) {
    int sh = 24 - pass * 8;
    unsigned pmask = pass ? (0xFFFFFFFFu << (sh + 8)) : 0u;
    if (tid < 256) hist[tid] = 0;
    __syncthreads();
#pragma unroll
    for (int q = 0; q < 4; ++q) {
      unsigned v = zb[q];
      if ((v & pmask) == (prefix & pmask)) atomicAdd(&hist[(v >> sh) & 255], 1u);
    }
    __syncthreads();
    if (tid == 0) {
      unsigned acc = 0;
      int bsel = 0;
      for (int i = 255; i >= 0; --i) {
        unsigned c = hist[i];
        if (acc + c >= kk) { bsel = i; s_kk = kk - acc; break; }
        acc += c;
      }
      s_prefix = prefix | ((unsigned)bsel << sh);
    }
    __syncthreads();
    prefix = s_prefix; kk = s_kk;
    __syncthreads();
  }
  // prefix = bit pattern of the K-th largest z (ties counted)
  if (tid == 0) { s_cgt = 0; s_ceq = 0; }
  __syncthreads();
  int cg = 0, ce = 0;
#pragma unroll
  for (int q = 0; q < 4; ++q) {
    if (zb[q] > prefix) ++cg;
    else if (zb[q] == prefix) ++ce;
  }
  if (cg) atomicAdd(&s_cgt, cg);
  if (ce) atomicAdd(&s_ceq, ce);
  __syncthreads();
  int need = K - s_cgt;
  bool allEq = (s_ceq == need);
  float* grow = g + b * T_;
#pragma unroll
  for (int q = 0; q < 4; ++q) {
    int t = tid + q * 1024;
    unsigned v = zb[q];
    if (v > prefix) grow[t] = 1.f;
    else if (v < prefix) grow[t] = 0.f;
    else if (allEq) grow[t] = 1.f;
  }
  __syncthreads();
  if (!allEq && tid == 0) {
    int cnt = 0;
    for (int t = 0; t < T_; ++t) {
      if (__float_as_uint(zrow[t]) == prefix) { grow[t] = (cnt < need) ? 1.f : 0.f; ++cnt; }
    }
  }
  if (b == 0 && tid == 0) {
    float s = 0.f;
    for (int i = 0; i < B_; ++i) s += rowent[i];
    out_scalar[0] = s * (1.f / B_);
  }
}

extern "C" void kernel_launch(void* const* d_in, const int* in_sizes, int n_in,
                              void* d_out, int out_size, void* d_ws, size_t ws_size,
                              hipStream_t stream)
{
  const float* emb  = (const float*)d_in[0];
  const float* attn = (const float*)d_in[1];
  const float* lnw  = (const float*)d_in[2];
  const float* lnb  = (const float*)d_in[3];
  const float* fc1w = (const float*)d_in[4];
  const float* fc1b = (const float*)d_in[5];
  const float* fc2w = (const float*)d_in[6];
  const float* fc2b = (const float*)d_in[7];

  float* out = (float*)d_out;
  float* g  = out;
  float* z  = out + N_TOK;
  float* ns = out + 2 * N_TOK;

  float* mu      = (float*)d_ws;                    // (unused slot, layout kept)
  float* rstd    = mu + N_TOK;                      // (unused slot, layout kept)
  float* partial = rstd + N_TOK;                    // NHT*N_TOK
  float* rowent  = partial + (size_t)NHT * N_TOK;   // 16
  float* rowK    = rowent + 16;                     // 16
  f16x8* whi     = (f16x8*)(rowK + 16);             // WCHUNKS
  f16x8* wlo     = whi + WCHUNKS;
  f16x8* ahi     = wlo + WCHUNKS;                   // ACHUNKS
  f16x8* alo     = ahi + ACHUNKS;

  wsplit_kernel<<<(WCHUNKS + 255) / 256, 256, 0, stream>>>(fc1w, whi, wlo);
  lnasplit_kernel<<<NG16, 256, 0, stream>>>(emb, attn, lnw, lnb, ahi, alo);
  mfma_score_v7<<<8 * 32 * NHT, 512, 0, stream>>>(ahi, alo, whi, wlo, fc1b, fc2w, partial);
  softmax_kernel<<<B_, 1024, 0, stream>>>(partial, fc2b, attn, z, rowent, rowK);
  topk_kernel<<<B_, 1024, 0, stream>>>(z, g, rowent, rowK, ns);
}

// Round 4
// 1032.273 us; speedup vs baseline: 1.1485x; 1.1143x over previous
//
#include <hip/hip_runtime.h>
#include <math.h>

#define B_ 16
#define T_ 4096
#define D_ 1024
#define HID_ 1365
#define NPAD 1408            // 88*16
#define NGRP 88              // NPAD/16
#define N_TOK (B_*T_)
#define RHO_ 0.2f
#define LN_EPS_ 1e-5f
#define SC 1024.0f
#define INV_SC2 (1.0f/(1024.0f*1024.0f))

#define NHT 11               // h-tiles of 128
#define WCHUNKS (NGRP*32*4*16)       // 180224 f16x8 chunks
#define NG16 4096            // 16-token groups
#define ACHUNKS ((size_t)NG16*32*64) // 8388608 f16x8 chunks per buffer

typedef _Float16 f16x8 __attribute__((ext_vector_type(8)));
typedef float f32x4 __attribute__((ext_vector_type(4)));

// ---------------- Kernel 1b: split fc1_w (x1024) into hi/lo f16 in MFMA-frag order ---
__global__ __launch_bounds__(256) void wsplit_kernel(
    const float* __restrict__ fc1w, f16x8* __restrict__ whi, f16x8* __restrict__ wlo)
{
  int c = blockIdx.x * 256 + threadIdx.x;
  if (c >= WCHUNKS) return;
  int ln = c & 15, q = (c >> 4) & 3, ks = (c >> 6) & 31, g = c >> 11;
  int n = g * 16 + ln;
  int k = ks * 32 + q * 8;
  f16x8 hi, lo;
#pragma unroll
  for (int j = 0; j < 8; ++j) {
    float v = (n < HID_) ? fc1w[(size_t)n * D_ + k + j] * SC : 0.f;
    _Float16 h = (_Float16)v;
    hi[j] = h;
    lo[j] = (_Float16)(v - (float)h);
  }
  whi[c] = hi;
  wlo[c] = lo;
}

// ---------------- Kernel 1c (fused): LN stats + LN-apply + hi/lo split, frag order ---
#define FSTR 1028
__global__ __launch_bounds__(256, 2) void lnasplit_kernel(
    const float* __restrict__ emb, const float* __restrict__ attn,
    const float* __restrict__ lnw, const float* __restrict__ lnb,
    f16x8* __restrict__ ahi, f16x8* __restrict__ alo)
{
  __shared__ float tile[16 * FSTR];
  __shared__ float smu[16], srs[16];
  int tid = threadIdx.x;
  int g = blockIdx.x;
  int wave = tid >> 6, lane = tid & 63;
#pragma unroll
  for (int it = 0; it < 16; ++it) {
    int idx = tid + it * 256;
    int row = idx >> 8, c4 = idx & 255;
    float a = attn[g * 16 + row];
    float4 v = *reinterpret_cast<const float4*>(
        emb + (size_t)(g * 16 + row) * D_ + c4 * 4);
    v.x *= a; v.y *= a; v.z *= a; v.w *= a;
    *reinterpret_cast<float4*>(&tile[row * FSTR + c4 * 4]) = v;
  }
  __syncthreads();
#pragma unroll
  for (int r4 = 0; r4 < 4; ++r4) {
    int row = wave * 4 + r4;
    float s = 0.f, sq = 0.f;
#pragma unroll
    for (int q = 0; q < 4; ++q) {
      float4 v = *reinterpret_cast<const float4*>(&tile[row * FSTR + lane * 4 + q * 256]);
      s  += v.x + v.y + v.z + v.w;
      sq += v.x * v.x + v.y * v.y + v.z * v.z + v.w * v.w;
    }
#pragma unroll
    for (int off = 32; off > 0; off >>= 1) {
      s  += __shfl_down(s, off, 64);
      sq += __shfl_down(sq, off, 64);
    }
    if (lane == 0) {
      float m = s * (1.f / D_);
      float var = sq * (1.f / D_) - m * m;
      if (var < 0.f) var = 0.f;
      smu[row] = m;
      srs[row] = 1.f / sqrtf(var + LN_EPS_);
    }
  }
  __syncthreads();
#pragma unroll
  for (int it = 0; it < 8; ++it) {
    int idx = tid + it * 256;
    int ksl = idx >> 6, l = idx & 63;
    int ln = l & 15, q = l >> 4;
    float rs = srs[ln];
    float nmr = -smu[ln] * rs;
    int colbase = ksl * 32 + q * 8;
    float4 e0 = *reinterpret_cast<const float4*>(&tile[ln * FSTR + colbase]);
    float4 e1 = *reinterpret_cast<const float4*>(&tile[ln * FSTR + colbase + 4]);
    float ev[8] = {e0.x, e0.y, e0.z, e0.w, e1.x, e1.y, e1.z, e1.w};
    f16x8 hi, lo;
#pragma unroll
    for (int j = 0; j < 8; ++j) {
      int kg = colbase + j;
      float wv = lnw[kg], bv = lnb[kg];
      float y = fmaf(ev[j] * rs, wv, fmaf(nmr, wv, bv)) * SC;
      _Float16 h = (_Float16)y;
      hi[j] = h;
      lo[j] = (_Float16)(y - (float)h);
    }
    size_t c = (size_t)(g * 32 + ksl) * 64 + l;
    ahi[c] = hi;
    alo[c] = lo;
  }
}

// ---------------- Kernel 2 (v8): barrier-free frag streaming + reg double-buffer ----
// Back to v4's no-LDS no-barrier structure (which hit 35.8% with ZERO prefetch),
// plus an explicit one-K-step register prefetch into a second named set. The
// compiler emits counted vmcnt (wait only the older 16 loads), so loads+addr-VALU
// for step k+1 run under the 48 MFMAs of step k on separate pipes. No asm, no
// sched_barrier — full compiler scheduling freedom (m141 lesson).
// 256 thr = 4 waves 2x2; wave tile 64 tok x 64 h; accumulation order unchanged.
__global__ __launch_bounds__(256, 2) void mfma_score_v8(
    const f16x8* __restrict__ ahi, const f16x8* __restrict__ alo,
    const f16x8* __restrict__ whi, const f16x8* __restrict__ wlo,
    const float* __restrict__ fc1b, const float* __restrict__ fc2w,
    float* __restrict__ partial)
{
  __shared__ float red[2][128];
  int tid = threadIdx.x, lane = tid & 63;
  int w = tid >> 6, wrow = w & 1, wcol = w >> 1;
  // XCD-aware swizzle: the 11 ht-blocks of one 128-token tile stay on one XCD
  int flat = blockIdx.x;            // 0..5631 = 8 XCDs * (64 tb * 11 ht)
  int xcd = flat & 7, j = flat >> 3;
  int tb = xcd * 64 + j / NHT;      // 0..511 token-tiles of 128
  int ht = j % NHT;                 // 0..10
  int g0 = tb * 8 + wrow * 4;       // 4 token-groups of 16 per wave
  int gb0 = ht * 8 + wcol * 4;      // 4 h-groups of 16 per wave
  int ln16 = lane & 15, quad = lane >> 4;

  const f16x8* srcAh = ahi + (size_t)g0 * 2048 + lane;   // + mi*2048 + ks*64
  const f16x8* srcAl = alo + (size_t)g0 * 2048 + lane;
  const f16x8* srcBh = whi + (size_t)gb0 * 2048 + lane;  // + nj*2048 + ks*64
  const f16x8* srcBl = wlo + (size_t)gb0 * 2048 + lane;

  f32x4 acc[4][4];
#pragma unroll
  for (int i = 0; i < 4; ++i)
#pragma unroll
    for (int j2 = 0; j2 < 4; ++j2) acc[i][j2] = (f32x4)0.f;

  f16x8 Pah[4], Pal[4], Pbh[4], Pbl[4];
  f16x8 Qah[4], Qal[4], Qbh[4], Qbl[4];

#define LOADSET(S, KS)                                           \
  do {                                                           \
    _Pragma("unroll")                                            \
    for (int mi = 0; mi < 4; ++mi) {                             \
      S##ah[mi] = srcAh[(size_t)mi * 2048 + (size_t)(KS) * 64];  \
      S##al[mi] = srcAl[(size_t)mi * 2048 + (size_t)(KS) * 64];  \
    }                                                            \
    _Pragma("unroll")                                            \
    for (int nj = 0; nj < 4; ++nj) {                             \
      S##bh[nj] = srcBh[(size_t)nj * 2048 + (size_t)(KS) * 64];  \
      S##bl[nj] = srcBl[(size_t)nj * 2048 + (size_t)(KS) * 64];  \
    }                                                            \
  } while (0)

#define MFMASET(S)                                               \
  do {                                                           \
    _Pragma("unroll")                                            \
    for (int mi = 0; mi < 4; ++mi)                               \
      _Pragma("unroll")                                          \
      for (int nj = 0; nj < 4; ++nj) {                           \
        acc[mi][nj] = __builtin_amdgcn_mfma_f32_16x16x32_f16(S##ah[mi], S##bh[nj], acc[mi][nj], 0, 0, 0); \
        acc[mi][nj] = __builtin_amdgcn_mfma_f32_16x16x32_f16(S##al[mi], S##bh[nj], acc[mi][nj], 0, 0, 0); \
        acc[mi][nj] = __builtin_amdgcn_mfma_f32_16x16x32_f16(S##ah[mi], S##bl[nj], acc[mi][nj], 0, 0, 0); \
      }                                                          \
  } while (0)

  LOADSET(P, 0);
#pragma unroll 1
  for (int ks = 0; ks < 32; ks += 2) {
    LOADSET(Q, ks + 1);      // prefetch k+1 while MFMA(k) runs (counted vmcnt)
    MFMASET(P);
    if (ks + 2 < 32) LOADSET(P, ks + 2);
    MFMASET(Q);
  }

#undef LOADSET
#undef MFMASET

  // ---- epilogue: bias + exact GELU + fc2 weight, reduce over hidden ----
  float s[4][4];
#pragma unroll
  for (int mi = 0; mi < 4; ++mi)
#pragma unroll
    for (int r = 0; r < 4; ++r) s[mi][r] = 0.f;
#pragma unroll
  for (int nj = 0; nj < 4; ++nj) {
    int h = (gb0 + nj) * 16 + ln16;
    float b1 = 0.f, w2 = 0.f;
    if (h < HID_) { b1 = fc1b[h]; w2 = fc2w[h]; }
#pragma unroll
    for (int mi = 0; mi < 4; ++mi)
#pragma unroll
      for (int r = 0; r < 4; ++r) {
        float v = acc[mi][nj][r] * INV_SC2 + b1;
        float gel = 0.5f * v * (1.f + erff(v * 0.70710678118654752440f));
        s[mi][r] = fmaf(gel, w2, s[mi][r]);
      }
  }
#pragma unroll
  for (int mi = 0; mi < 4; ++mi)
#pragma unroll
    for (int r = 0; r < 4; ++r) {
      float v = s[mi][r];
      v += __shfl_xor(v, 1, 64);
      v += __shfl_xor(v, 2, 64);
      v += __shfl_xor(v, 4, 64);
      v += __shfl_xor(v, 8, 64);
      s[mi][r] = v;
    }
  if (ln16 == 0) {
#pragma unroll
    for (int mi = 0; mi < 4; ++mi)
#pragma unroll
      for (int r = 0; r < 4; ++r)
        red[wcol][wrow * 64 + mi * 16 + quad * 4 + r] = s[mi][r];
  }
  __syncthreads();
  if (tid < 128)
    partial[(size_t)ht * N_TOK + tb * 128 + tid] = red[0][tid] + red[1][tid];
}

// ---------------- Kernel 3: slab-reduce + masked softmax + entropy + K + z ----------
__global__ __launch_bounds__(1024) void softmax_kernel(
    const float* __restrict__ partial, const float* __restrict__ fc2b,
    const float* __restrict__ attn,
    float* __restrict__ out_z, float* __restrict__ rowent, float* __restrict__ rowK)
{
  __shared__ float buf[1024];
  int b = blockIdx.x, tid = threadIdx.x;
  const float* arow = attn + b * T_;
  float sv[4], av[4];
  float f2b = fc2b[0];
#pragma unroll
  for (int q = 0; q < 4; ++q) {
    int t = tid + q * 1024;
    av[q] = arow[t];
    float sc = f2b;
#pragma unroll
    for (int p = 0; p < NHT; ++p) sc += partial[(size_t)p * N_TOK + b * T_ + t];
    sv[q] = (av[q] == 0.f) ? -1e9f : sc;
  }
  float m = fmaxf(fmaxf(sv[0], sv[1]), fmaxf(sv[2], sv[3]));
  buf[tid] = m; __syncthreads();
  for (int s = 512; s > 0; s >>= 1) { if (tid < s) buf[tid] = fmaxf(buf[tid], buf[tid + s]); __syncthreads(); }
  m = buf[0]; __syncthreads();
  float e[4]; float es = 0.f, as = 0.f;
#pragma unroll
  for (int q = 0; q < 4; ++q) { e[q] = expf(sv[q] - m); es += e[q]; as += av[q]; }
  buf[tid] = es; __syncthreads();
  for (int s = 512; s > 0; s >>= 1) { if (tid < s) buf[tid] += buf[tid + s]; __syncthreads(); }
  es = buf[0]; __syncthreads();
  buf[tid] = as; __syncthreads();
  for (int s = 512; s > 0; s >>= 1) { if (tid < s) buf[tid] += buf[tid + s]; __syncthreads(); }
  as = buf[0]; __syncthreads();
  float K = fmaxf(1.f, rintf(RHO_ * as));
  float inv = 1.f / es;
  float ent = 0.f;
#pragma unroll
  for (int q = 0; q < 4; ++q) {
    float p = e[q] * inv;
    out_z[b * T_ + tid + q * 1024] = K * p;
    ent -= p * logf(p + 1e-12f);
  }
  buf[tid] = ent; __syncthreads();
  for (int s = 512; s > 0; s >>= 1) { if (tid < s) buf[tid] += buf[tid + s]; __syncthreads(); }
  if (tid == 0) {
    rowent[b] = buf[0] / logf(fmaxf(as, 1.f));
    rowK[b] = K;
  }
}

// ---------------- Kernel 4 (v2): radix-256 select top-K (stable ties) + scalar out --
// z >= +0 always (K*p, p>=0), so uint bit pattern is order-isomorphic to float.
__global__ __launch_bounds__(1024) void topk_kernel(
    const float* __restrict__ zall, float* __restrict__ g,
    const float* __restrict__ rowent, const float* __restrict__ rowK,
    float* __restrict__ out_scalar)
{
  __shared__ unsigned hist[256];
  __shared__ unsigned s_prefix, s_kk;
  __shared__ int s_cgt, s_ceq;
  int b = blockIdx.x, tid = threadIdx.x;
  const float* zrow = zall + b * T_;
  unsigned zb[4];
#pragma unroll
  for (int q = 0; q < 4; ++q) zb[q] = __float_as_uint(zrow[tid + q * 1024]);
  int K = (int)rowK[b];

  unsigned prefix = 0;
  unsigned kk = (unsigned)K;          // 1-indexed rank from the top
#pragma unroll
  for (int pass = 0; pass < 4; ++pass) {
    int sh = 24 - pass * 8;
    unsigned pmask = pass ? (0xFFFFFFFFu << (sh + 8)) : 0u;
    if (tid < 256) hist[tid] = 0;
    __syncthreads();
#pragma unroll
    for (int q = 0; q < 4; ++q) {
      unsigned v = zb[q];
      if ((v & pmask) == (prefix & pmask)) atomicAdd(&hist[(v >> sh) & 255], 1u);
    }
    __syncthreads();
    if (tid == 0) {
      unsigned acc = 0;
      int bsel = 0;
      for (int i = 255; i >= 0; --i) {
        unsigned c = hist[i];
        if (acc + c >= kk) { bsel = i; s_kk = kk - acc; break; }
        acc += c;
      }
      s_prefix = prefix | ((unsigned)bsel << sh);
    }
    __syncthreads();
    prefix = s_prefix; kk = s_kk;
    __syncthreads();
  }
  // prefix = bit pattern of the K-th largest z (ties counted)
  if (tid == 0) { s_cgt = 0; s_ceq = 0; }
  __syncthreads();
  int cg = 0, ce = 0;
#pragma unroll
  for (int q = 0; q < 4; ++q) {
    if (zb[q] > prefix) ++cg;
    else if (zb[q] == prefix) ++ce;
  }
  if (cg) atomicAdd(&s_cgt, cg);
  if (ce) atomicAdd(&s_ceq, ce);
  __syncthreads();
  int need = K - s_cgt;
  bool allEq = (s_ceq == need);
  float* grow = g + b * T_;
#pragma unroll
  for (int q = 0; q < 4; ++q) {
    int t = tid + q * 1024;
    unsigned v = zb[q];
    if (v > prefix) grow[t] = 1.f;
    else if (v < prefix) grow[t] = 0.f;
    else if (allEq) grow[t] = 1.f;
  }
  __syncthreads();
  if (!allEq && tid == 0) {
    int cnt = 0;
    for (int t = 0; t < T_; ++t) {
      if (__float_as_uint(zrow[t]) == prefix) { grow[t] = (cnt < need) ? 1.f : 0.f; ++cnt; }
    }
  }
  if (b == 0 && tid == 0) {
    float s = 0.f;
    for (int i = 0; i < B_; ++i) s += rowent[i];
    out_scalar[0] = s * (1.f / B_);
  }
}

extern "C" void kernel_launch(void* const* d_in, const int* in_sizes, int n_in,
                              void* d_out, int out_size, void* d_ws, size_t ws_size,
                              hipStream_t stream)
{
  const float* emb  = (const float*)d_in[0];
  const float* attn = (const float*)d_in[1];
  const float* lnw  = (const float*)d_in[2];
  const float* lnb  = (const float*)d_in[3];
  const float* fc1w = (const float*)d_in[4];
  const float* fc1b = (const float*)d_in[5];
  const float* fc2w = (const float*)d_in[6];
  const float* fc2b = (const float*)d_in[7];

  float* out = (float*)d_out;
  float* g  = out;
  float* z  = out + N_TOK;
  float* ns = out + 2 * N_TOK;

  float* mu      = (float*)d_ws;                    // (unused slot, layout kept)
  float* rstd    = mu + N_TOK;                      // (unused slot, layout kept)
  float* partial = rstd + N_TOK;                    // NHT*N_TOK
  float* rowent  = partial + (size_t)NHT * N_TOK;   // 16
  float* rowK    = rowent + 16;                     // 16
  f16x8* whi     = (f16x8*)(rowK + 16);             // WCHUNKS
  f16x8* wlo     = whi + WCHUNKS;
  f16x8* ahi     = wlo + WCHUNKS;                   // ACHUNKS
  f16x8* alo     = ahi + ACHUNKS;

  wsplit_kernel<<<(WCHUNKS + 255) / 256, 256, 0, stream>>>(fc1w, whi, wlo);
  lnasplit_kernel<<<NG16, 256, 0, stream>>>(emb, attn, lnw, lnb, ahi, alo);
  mfma_score_v8<<<8 * 64 * NHT, 256, 0, stream>>>(ahi, alo, whi, wlo, fc1b, fc2w, partial);
  softmax_kernel<<<B_, 1024, 0, stream>>>(partial, fc2b, attn, z, rowent, rowK);
  topk_kernel<<<B_, 1024, 0, stream>>>(z, g, rowent, rowK, ns);
}